// Round 1
// baseline (423.090 us; speedup 1.0000x reference)
//
#include <hip/hip_runtime.h>
#include <hip/hip_bf16.h>

#define B_ 8
#define N_ 2048
#define D_ 128

typedef __bf16 bf16_t;
typedef __bf16 v8bf __attribute__((ext_vector_type(8)));
typedef float  v4f  __attribute__((ext_vector_type(4)));

// ---------------------------------------------------------------------------
// k_prep: WT[o][i] = (bf16)Ww[i][o]; AT[o][i] = (bf16)Aw[i][o].
// ---------------------------------------------------------------------------
__global__ __launch_bounds__(256) void k_prep(
    const float* __restrict__ Ww, const float* __restrict__ Aw,
    bf16_t* __restrict__ WT, bf16_t* __restrict__ AT)
{
    int idx = blockIdx.x * 256 + threadIdx.x;   // 0..16383
    int o = idx >> 7, i = idx & 127;
    WT[idx] = (bf16_t)Ww[i * D_ + o];
    AT[idx] = (bf16_t)Aw[i * D_ + o];
}

// ---------------------------------------------------------------------------
// k_hg (MFMA): h = x@W + b; g = h@A.  Block = 64 rows, 4 waves x 16 rows.
// ---------------------------------------------------------------------------
__global__ __launch_bounds__(256) void k_hg(
    const float* __restrict__ x, const float* __restrict__ Wb,
    const bf16_t* __restrict__ WT, const bf16_t* __restrict__ AT,
    bf16_t* __restrict__ hb, bf16_t* __restrict__ gb)
{
    int wave = threadIdx.x >> 6;
    int lane = threadIdx.x & 63;
    int q = lane >> 4;
    int c = lane & 15;
    int nrow0 = blockIdx.x * 64 + wave * 16;    // global flat row (b*N+n)

    __shared__ float pw_all[4][16][132];
    float (*pw)[132] = pw_all[wave];

    v8bf ax[4];
#pragma unroll
    for (int kc = 0; kc < 4; ++kc) {
        const float* src = x + (size_t)(nrow0 + c) * D_ + kc * 32 + q * 8;
        float4 f0 = *(const float4*)src;
        float4 f1 = *(const float4*)(src + 4);
        v8bf a;
        a[0]=(bf16_t)f0.x; a[1]=(bf16_t)f0.y; a[2]=(bf16_t)f0.z; a[3]=(bf16_t)f0.w;
        a[4]=(bf16_t)f1.x; a[5]=(bf16_t)f1.y; a[6]=(bf16_t)f1.z; a[7]=(bf16_t)f1.w;
        ax[kc] = a;
    }

#pragma unroll
    for (int ct = 0; ct < 8; ++ct) {
        float bias = Wb[ct * 16 + c];
        v4f acc = {bias, bias, bias, bias};
#pragma unroll
        for (int kc = 0; kc < 4; ++kc) {
            v8bf bw = *(const v8bf*)(WT + (size_t)(ct * 16 + c) * D_ + kc * 32 + q * 8);
            acc = __builtin_amdgcn_mfma_f32_16x16x32_bf16(ax[kc], bw, acc, 0, 0, 0);
        }
#pragma unroll
        for (int r = 0; r < 4; ++r) pw[q * 4 + r][ct * 16 + c] = acc[r];
    }
    __builtin_amdgcn_wave_barrier();

    v8bf ahf[4];
#pragma unroll
    for (int kc = 0; kc < 4; ++kc) {
        v4f p0 = *(const v4f*)&pw[c][kc * 32 + q * 8];
        v4f p1 = *(const v4f*)&pw[c][kc * 32 + q * 8 + 4];
        v8bf a;
#pragma unroll
        for (int j = 0; j < 4; ++j) { a[j] = (bf16_t)p0[j]; a[j+4] = (bf16_t)p1[j]; }
        ahf[kc] = a;
    }
    {
        int row = lane >> 2, seg = lane & 3;
#pragma unroll
        for (int v = 0; v < 4; ++v) {
            v8bf hv;
#pragma unroll
            for (int j = 0; j < 8; ++j) hv[j] = (bf16_t)pw[row][seg * 32 + v * 8 + j];
            *(v8bf*)(hb + (size_t)(nrow0 + row) * D_ + seg * 32 + v * 8) = hv;
        }
    }
    __builtin_amdgcn_wave_barrier();

#pragma unroll
    for (int ct = 0; ct < 8; ++ct) {
        v4f acc = {0.f, 0.f, 0.f, 0.f};
#pragma unroll
        for (int kc = 0; kc < 4; ++kc) {
            v8bf bw = *(const v8bf*)(AT + (size_t)(ct * 16 + c) * D_ + kc * 32 + q * 8);
            acc = __builtin_amdgcn_mfma_f32_16x16x32_bf16(ahf[kc], bw, acc, 0, 0, 0);
        }
#pragma unroll
        for (int r = 0; r < 4; ++r) pw[q * 4 + r][ct * 16 + c] = acc[r];
    }
    __builtin_amdgcn_wave_barrier();
    {
        int row = lane >> 2, seg = lane & 3;
#pragma unroll
        for (int v = 0; v < 4; ++v) {
            v8bf gv;
#pragma unroll
            for (int j = 0; j < 8; ++j) gv[j] = (bf16_t)pw[row][seg * 32 + v * 8 + j];
            *(v8bf*)(gb + (size_t)(nrow0 + row) * D_ + seg * 32 + v * 8) = gv;
        }
    }
}

// ---------------------------------------------------------------------------
// k_att v2: E tiles -> P~ = (adj>0)*exp(e) -> bf16 scalar stores + colsum.
// NO LDS (was the occupancy cap at 2 blocks/CU) -> direct bf16 stores from
// the MFMA accumulator layout (16-lane c-groups = 32B segments; both halves
// of each 64B line come from the same wave, L2 merges).
// Per-wave span shrunk 64n x 64m -> 32n x 128m: A-frag residency 128->64
// VGPRs, total demand ~130 -> 3 waves/SIMD (launch_bounds(256,3)).
// grid 2048: b(8, low bits for XCD spread) x nblk(64 x 32n) x mgrp(4 x 512m).
// Per 16-m tile: 8 adj + 8 B loads -> 16 MFMAs in 4 independent chains.
// ---------------------------------------------------------------------------
__global__ __launch_bounds__(256, 3) void k_att(
    const bf16_t* __restrict__ hb, const bf16_t* __restrict__ gb,
    const float* __restrict__ adj, float* __restrict__ colsum,
    bf16_t* __restrict__ Pt)
{
    int bid = blockIdx.x;
    int b = bid & 7;
    int rest = bid >> 3;          // 0..255
    int nblk = rest >> 2;         // 0..63   (32 n-rows)
    int mgrp = rest & 3;          // 0..3    (512 m-cols per block)
    int wave = threadIdx.x >> 6;
    int lane = threadIdx.x & 63;
    int q = lane >> 4;
    int c = lane & 15;
    int nbase = nblk * 32;
    int mwav = mgrp * 512 + wave * 128;
    const size_t hgoff = (size_t)b * N_ * D_;
    const float* adjb = adj + (size_t)b * N_ * N_;
    bf16_t* Pb = Pt + (size_t)b * N_ * N_;

    // A-frags: 2 n-subtiles x {g,h} (64 VGPRs, persistent)
    v8bf ag[2][4], ah[2][4];
#pragma unroll
    for (int sub = 0; sub < 2; ++sub)
#pragma unroll
        for (int kc = 0; kc < 4; ++kc) {
            size_t off = hgoff + (size_t)(nbase + sub * 16 + c) * D_ + kc * 32 + q * 8;
            ag[sub][kc] = *(const v8bf*)(gb + off);
            ah[sub][kc] = *(const v8bf*)(hb + off);
        }

    for (int t = 0; t < 8; ++t) {
        int mt = mwav + t * 16;
        // adj values: issue early, 8 independent 4B loads (64B-coalesced)
        float av[2][4];
#pragma unroll
        for (int sub = 0; sub < 2; ++sub)
#pragma unroll
            for (int r = 0; r < 4; ++r)
                av[sub][r] = adjb[(size_t)(nbase + sub * 16 + q * 4 + r) * N_ + mt + c];
        // B-frags: 8 independent 16B loads
        v8bf bh[4], bg[4];
#pragma unroll
        for (int kc = 0; kc < 4; ++kc) {
            size_t off = hgoff + (size_t)(mt + c) * D_ + kc * 32 + q * 8;
            bh[kc] = *(const v8bf*)(hb + off);
            bg[kc] = *(const v8bf*)(gb + off);
        }
        // 4 independent MFMA chains (2 subs x {g.h^T, h.g^T})
        v4f e0[2], e1[2];
#pragma unroll
        for (int sub = 0; sub < 2; ++sub) {
            e0[sub] = (v4f){0.f, 0.f, 0.f, 0.f};
            e1[sub] = (v4f){0.f, 0.f, 0.f, 0.f};
        }
#pragma unroll
        for (int kc = 0; kc < 4; ++kc)
#pragma unroll
            for (int sub = 0; sub < 2; ++sub) {
                e0[sub] = __builtin_amdgcn_mfma_f32_16x16x32_bf16(ag[sub][kc], bh[kc], e0[sub], 0, 0, 0);
                e1[sub] = __builtin_amdgcn_mfma_f32_16x16x32_bf16(ah[sub][kc], bg[kc], e1[sub], 0, 0, 0);
            }
        float cs = 0.f;
#pragma unroll
        for (int sub = 0; sub < 2; ++sub)
#pragma unroll
            for (int r = 0; r < 4; ++r) {
                float ev = e0[sub][r] + e1[sub][r];
                float ex = __expf(ev);
                float pv = (av[sub][r] > 0.f) ? ex : 0.f;
                cs += pv;
                Pb[(size_t)(nbase + sub * 16 + q * 4 + r) * N_ + mt + c] = (bf16_t)pv;
            }
        cs += __shfl_xor(cs, 16);
        cs += __shfl_xor(cs, 32);
        if (lane < 16) atomicAdd(&colsum[b * N_ + mt + lane], cs);
    }
}

// ---------------------------------------------------------------------------
// k_scaleT: hbTs[b][d][m] = h[b][m][d] * inv(colsum[b][m]).
// ---------------------------------------------------------------------------
__global__ __launch_bounds__(256) void k_scaleT(
    const bf16_t* __restrict__ hb, const float* __restrict__ colsum,
    bf16_t* __restrict__ hbTs)
{
    int bid = blockIdx.x;
    int b = bid >> 6;
    int rem = bid & 63;
    int nblk = rem >> 1;
    int dblk = rem & 1;
    int tid = threadIdx.x;
    __shared__ bf16_t sm[64][72];
    __shared__ float sinv[64];
    int n0 = nblk * 64, d0 = dblk * 64;
    int r = tid >> 3, cg = tid & 7;
#pragma unroll
    for (int rr = 0; rr < 2; ++rr) {
        int row = r + rr * 32;
        *(v8bf*)&sm[row][cg * 8] =
            *(const v8bf*)(hb + (size_t)(b * N_ + n0 + row) * D_ + d0 + cg * 8);
    }
    if (tid < 64) {
        float s = colsum[b * N_ + n0 + tid];
        sinv[tid] = (s > 0.f) ? 1.f / s : 0.f;
    }
    __syncthreads();
#pragma unroll
    for (int rr = 0; rr < 2; ++rr) {
        int dr = r + rr * 32;
        v8bf v;
#pragma unroll
        for (int jj = 0; jj < 8; ++jj)
            v[jj] = (bf16_t)((float)sm[cg * 8 + jj][dr] * sinv[cg * 8 + jj]);
        *(v8bf*)(hbTs + (size_t)(b * D_ + d0 + dr) * N_ + n0 + cg * 8) = v;
    }
}

// ---------------------------------------------------------------------------
// k_out v2: h_prime = Pt @ hbTs, fused relu+gate+output epilogue.
// grid 256 (b=bid&7), 512 thr = 8 waves. Wave = (nsub 0..3) x (dhalf 0..1):
// owns a DISJOINT 16n x 64d output slice, reduces the FULL m=2048 itself.
// -> zero inter-wave combine (old version: 8 serialized __syncthreads
//    rounds at 1 block/CU). One barrier before the epilogue.
// Per 32-m chunk: 1 A + 4 B loads -> 4 MFMAs (4 indep acc chains).
// A lines shared by 2 waves, B lines by 4 waves -> L1 hits.
// ---------------------------------------------------------------------------
__global__ __launch_bounds__(512, 2) void k_out(
    const bf16_t* __restrict__ Pt, const bf16_t* __restrict__ hbTs,
    const float* __restrict__ x, const float* __restrict__ gw,
    const float* __restrict__ gbias, float* __restrict__ out)
{
    int bid = blockIdx.x;
    int b = bid & 7;
    int nblk = bid >> 3;          // 0..31
    int tid = threadIdx.x;
    int wave = tid >> 6;
    int lane = tid & 63;
    int q = lane >> 4;
    int c = lane & 15;
    int nbase = nblk * 64;
    int nsub = wave & 3;          // 16 n-rows
    int dhalf = wave >> 2;        // 64 d-cols

    __shared__ float hp[64][132];

    const bf16_t* hTb = hbTs + (size_t)b * D_ * N_;
    const bf16_t* Pb  = Pt + (size_t)b * N_ * N_;
    const bf16_t* Arow = Pb + (size_t)(nbase + nsub * 16 + c) * N_;

    v4f acc[4];
#pragma unroll
    for (int dt = 0; dt < 4; ++dt) acc[dt] = (v4f){0.f, 0.f, 0.f, 0.f};

    for (int ch = 0; ch < 64; ++ch) {
        int mch = ch * 32;
        v8bf a = *(const v8bf*)(Arow + mch + q * 8);
        v8bf vt[4];
#pragma unroll
        for (int dt = 0; dt < 4; ++dt)
            vt[dt] = *(const v8bf*)(hTb + (size_t)(dhalf * 64 + dt * 16 + c) * N_ + mch + q * 8);
#pragma unroll
        for (int dt = 0; dt < 4; ++dt)
            acc[dt] = __builtin_amdgcn_mfma_f32_16x16x32_bf16(a, vt[dt], acc[dt], 0, 0, 0);
    }

    // each wave writes its disjoint slice; one barrier total
#pragma unroll
    for (int dt = 0; dt < 4; ++dt)
#pragma unroll
        for (int r = 0; r < 4; ++r)
            hp[nsub * 16 + q * 4 + r][dhalf * 64 + dt * 16 + c] = acc[dt][r];
    __syncthreads();

    // fused epilogue: 512 thr = 64 rows x 8 segs x 16 d
    int row = tid >> 3;
    int seg = tid & 7;
    size_t g = (size_t)b * N_ + nbase + row;
    const float* xr = x + g * D_ + seg * 16;
    float xv[16], hv[16];
#pragma unroll
    for (int j = 0; j < 16; j += 4) {
        float4 f = *(const float4*)(xr + j);
        xv[j] = f.x; xv[j+1] = f.y; xv[j+2] = f.z; xv[j+3] = f.w;
    }
#pragma unroll
    for (int j = 0; j < 16; ++j) hv[j] = fmaxf(hp[row][seg * 16 + j], 0.f);
    float part = 0.f;
#pragma unroll
    for (int j = 0; j < 16; ++j)
        part += xv[j] * gw[seg * 16 + j] + hv[j] * gw[D_ + seg * 16 + j];
    part += __shfl_xor(part, 1);
    part += __shfl_xor(part, 2);
    part += __shfl_xor(part, 4);
    float coeff = 1.f / (1.f + __expf(-(part + gbias[0])));
    float* orow = out + g * D_ + seg * 16;
#pragma unroll
    for (int j = 0; j < 16; j += 4) {
        float4 o;
        o.x = coeff * xv[j]   + (1.f - coeff) * hv[j];
        o.y = coeff * xv[j+1] + (1.f - coeff) * hv[j+1];
        o.z = coeff * xv[j+2] + (1.f - coeff) * hv[j+2];
        o.w = coeff * xv[j+3] + (1.f - coeff) * hv[j+3];
        *(float4*)(orow + j) = o;
    }
}

// ---------------------------------------------------------------------------
extern "C" void kernel_launch(void* const* d_in, const int* in_sizes, int n_in,
                              void* d_out, int out_size, void* d_ws, size_t ws_size,
                              hipStream_t stream)
{
    const float* x     = (const float*)d_in[0];
    const float* adj   = (const float*)d_in[1];
    const float* Ww    = (const float*)d_in[2];
    const float* Wb    = (const float*)d_in[3];
    const float* Aw    = (const float*)d_in[4];
    const float* gw    = (const float*)d_in[5];
    const float* gbias = (const float*)d_in[6];
    float* out = (float*)d_out;

    char* ws = (char*)d_ws;
    bf16_t* hb     = (bf16_t*)(ws);                          // 4 MB
    bf16_t* gb     = (bf16_t*)(ws + (4 << 20));              // 4 MB
    bf16_t* hbTs   = (bf16_t*)(ws + (8 << 20));              // 4 MB
    float*  colsum = (float*)(ws + (12 << 20));              // 64 KB
    bf16_t* Pt     = (bf16_t*)(ws + (17 << 20));             // 64 MB
    bf16_t* WT     = (bf16_t*)(ws + (81 << 20));             // 32 KB
    bf16_t* AT     = (bf16_t*)(ws + (81 << 20) + (32 << 10));// 32 KB

    hipMemsetAsync(colsum, 0, B_ * N_ * sizeof(float), stream);
    k_prep<<<64, 256, 0, stream>>>(Ww, Aw, WT, AT);
    k_hg<<<B_ * N_ / 64, 256, 0, stream>>>(x, Wb, WT, AT, hb, gb);
    k_att<<<2048, 256, 0, stream>>>(hb, gb, adj, colsum, Pt);
    k_scaleT<<<512, 256, 0, stream>>>(hb, colsum, hbTs);
    k_out<<<256, 512, 0, stream>>>(Pt, hbTs, x, gw, gbias, out);
}